// Round 1
// baseline (174.324 us; speedup 1.0000x reference)
//
#include <hip/hip_runtime.h>
#include <hip/hip_bf16.h>

#define BB 2
#define TT 2048
#define CCH 1024
#define NHH 16
#define HDD 64
#define M_TOK (BB*TT)      // 4096
#define N_QKV (3*CCH)      // 3072

typedef __attribute__((ext_vector_type(8))) short bf16x8;
typedef __attribute__((ext_vector_type(4))) float f32x4;
typedef unsigned short u16;
typedef unsigned int u32;

__device__ __forceinline__ u16 f2bf(float f) {
    union { float f; u32 u; } v; v.f = f;
    u32 u = v.u;
    u32 r = (u + 0x7FFFu + ((u >> 16) & 1u)) >> 16;
    return (u16)r;
}

// pack hi16(a),hi16(b) -> u32 {b.hi<<16 | a.hi} with +0x8000 rounding
__device__ __forceinline__ u32 pk_bf16(float a, float b) {
    u32 ua = __float_as_uint(a) + 0x8000u;
    u32 ub = __float_as_uint(b) + 0x8000u;
    return __builtin_amdgcn_perm(ub, ua, 0x07060302u);
}

__device__ __forceinline__ void async_copy16(const void* g, void* l) {
    __builtin_amdgcn_global_load_lds((__attribute__((address_space(1))) void*)g,
                                     (__attribute__((address_space(3))) void*)l,
                                     16, 0, 0);
}

// ---------------- pre-pass kernels ----------------

__global__ __launch_bounds__(256) void cast_bf16_kernel(
    const float* __restrict__ src, u16* __restrict__ dst, int n4) {
    int i = blockIdx.x * 256 + threadIdx.x;
    if (i < n4) {
        float4 f = ((const float4*)src)[i];
        ushort4 o;
        o.x = f2bf(f.x); o.y = f2bf(f.y); o.z = f2bf(f.z); o.w = f2bf(f.w);
        ((ushort4*)dst)[i] = o;
    }
}

// src [R][Cn] fp32 -> dst [Cn][R] bf16; rows of dst with index < scale_rows get *= sc
__global__ __launch_bounds__(256) void transpose_bf16_kernel(
    const float* __restrict__ src, u16* __restrict__ dst, int R, int Cn,
    int scale_rows, float sc) {
    __shared__ float tile[32][33];
    int c0 = blockIdx.x * 32, r0 = blockIdx.y * 32;
    int tx = threadIdx.x, ty = threadIdx.y;
#pragma unroll
    for (int i = ty; i < 32; i += 8)
        tile[i][tx] = src[(size_t)(r0 + i) * Cn + c0 + tx];
    __syncthreads();
#pragma unroll
    for (int i = ty; i < 32; i += 8) {
        float v = tile[tx][i];
        if (c0 + i < scale_rows) v *= sc;
        dst[(size_t)(c0 + i) * R + r0 + tx] = f2bf(v);
    }
}

// ---------------- shared GEMM K-loop, BK=64, XOR-swizzled LDS ----------------
// A[M][K] x Bt[N][K]^T. M-tile 128, N-tile NJ*32 (NJ=4 -> 128, NJ=2 -> 64).
// LDS rows [row][64] with 16B chunk c stored at c ^ (row&7)  (swizzle applied
// on the GLOBAL address during global_load_lds staging; lane-contiguous LDS).
// Fragment ds_read_b128 then hits all 32 banks with exactly 2 lanes/bank (free).
// SWAP=1: mfma(B,A) -> acc holds C^T fragment (token on lane&15, cols on regs).

template<int SWAP, int NJ>
__device__ __forceinline__ void gemm_kloop64(
    const u16* __restrict__ A, const u16* __restrict__ Bt, int K,
    int m0, int n0, int t, u16* __restrict__ As, u16* __restrict__ Bs,
    f32x4 (&acc)[4][4])
{
    int lane = t & 63, w = t >> 6;
    int mw = (w >> 1) * 64, nw = (w & 1) * (NJ * 16);
    int mr = lane & 15, quad = lane >> 4;
    int lr = lane >> 3;                 // row-in-group 0..7
    int cswz = (lane & 7) ^ lr;         // swizzled 16B-chunk on the global side

    const u16* gA[4]; u16* lA[4];
#pragma unroll
    for (int p = 0; p < 4; ++p) {
        int grp = w * 4 + p;            // 16 groups x 8 rows = 128
        gA[p] = A + (size_t)(m0 + grp * 8 + lr) * K + cswz * 8;
        lA[p] = As + ((size_t)grp * 64 + lane) * 8;
    }
    const u16* gB[4]; u16* lB[4];
#pragma unroll
    for (int p = 0; p < NJ; ++p) {
        int grp = w * NJ + p;           // NJ groups per wave
        gB[p] = Bt + (size_t)(n0 + grp * 8 + lr) * K + cswz * 8;
        lB[p] = Bs + ((size_t)grp * 64 + lane) * 8;
    }

    int swm = mr & 7;
    for (int k0 = 0; k0 < K; k0 += 64) {
#pragma unroll
        for (int p = 0; p < 4; ++p) async_copy16(gA[p] + k0, lA[p]);
#pragma unroll
        for (int p = 0; p < NJ; ++p) async_copy16(gB[p] + k0, lB[p]);
        __syncthreads();
#pragma unroll
        for (int kk = 0; kk < 2; ++kk) {
            bf16x8 af[4], bfr[4];
#pragma unroll
            for (int i = 0; i < 4; ++i) {
                int r = mw + i * 16 + mr;
                af[i] = *(const bf16x8*)&As[r * 64 + (((kk * 4 + quad) ^ swm) << 3)];
            }
#pragma unroll
            for (int j = 0; j < NJ; ++j) {
                int r = nw + j * 16 + mr;
                bfr[j] = *(const bf16x8*)&Bs[r * 64 + (((kk * 4 + quad) ^ swm) << 3)];
            }
#pragma unroll
            for (int i = 0; i < 4; ++i)
#pragma unroll
                for (int j = 0; j < NJ; ++j) {
                    if (SWAP)
                        acc[i][j] = __builtin_amdgcn_mfma_f32_16x16x32_bf16(bfr[j], af[i], acc[i][j], 0, 0, 0);
                    else
                        acc[i][j] = __builtin_amdgcn_mfma_f32_16x16x32_bf16(af[i], bfr[j], acc[i][j], 0, 0, 0);
                }
        }
        __syncthreads();
    }
}

// ---------------- merged QKV GEMM: one 768-block dispatch ----------------
// Parts 0/1 (Q/K): swapped loop -> [bh][t][d] bf16, 8B stores along d.
// Part 2 (V): normal loop -> Vt [bh][d][t] bf16, 8B stores along t.

__global__ __launch_bounds__(256, 3) void qkv_gemm_kernel(
    const u16* __restrict__ A, const u16* __restrict__ Bt,
    u16* __restrict__ Qo, u16* __restrict__ Ko, u16* __restrict__ Vto)
{
    __shared__ u16 As[128 * 64];
    __shared__ u16 Bs[128 * 64];
    int t = threadIdx.x;
    int m0 = blockIdx.y * 128, n0 = blockIdx.x * 128;
    int part = n0 >> 10;
    int lane = t & 63, w = t >> 6;
    int mw = (w >> 1) * 64, nw = (w & 1) * 64;
    int mr = lane & 15, quad = lane >> 4;

    f32x4 zero = {0.f, 0.f, 0.f, 0.f};
    f32x4 acc[4][4];
#pragma unroll
    for (int i = 0; i < 4; ++i)
#pragma unroll
        for (int j = 0; j < 4; ++j) acc[i][j] = zero;

    if (part < 2) {   // block-uniform branch
        gemm_kloop64<1, 4>(A, Bt, CCH, m0, n0, t, As, Bs, acc);
        u16* dstp = part ? Ko : Qo;
#pragma unroll
        for (int i = 0; i < 4; ++i)
#pragma unroll
            for (int j = 0; j < 4; ++j) {
                int tok = m0 + mw + i * 16 + mr;
                int cg0 = n0 + nw + j * 16 + quad * 4;
                int cc = cg0 & 1023;
                int h = cc >> 6, d0 = cc & 63;
                int b = tok >> 11, tt = tok & 2047;
                int bh = b * NHH + h;
                uint2 o;
                o.x = pk_bf16(acc[i][j][0], acc[i][j][1]);
                o.y = pk_bf16(acc[i][j][2], acc[i][j][3]);
                *(uint2*)&dstp[((size_t)bh * TT + tt) * HDD + d0] = o;
            }
    } else {
        gemm_kloop64<0, 4>(A, Bt, CCH, m0, n0, t, As, Bs, acc);
#pragma unroll
        for (int i = 0; i < 4; ++i)
#pragma unroll
            for (int j = 0; j < 4; ++j) {
                int t0 = m0 + mw + i * 16 + quad * 4;
                int cg = n0 + nw + j * 16 + mr;
                int cc = cg & 1023;
                int h = cc >> 6, d = cc & 63;
                int b = t0 >> 11, tt0 = t0 & 2047;
                int bh = b * NHH + h;
                uint2 o;
                o.x = pk_bf16(acc[i][j][0], acc[i][j][1]);
                o.y = pk_bf16(acc[i][j][2], acc[i][j][3]);
                *(uint2*)&Vto[((size_t)bh * HDD + d) * TT + tt0] = o;
            }
    }
}

// ---------------- output projection: 128x64 tiles, 512 blocks (2/CU) ----------------

__global__ __launch_bounds__(256) void proj_gemm_kernel(
    const u16* __restrict__ A, const u16* __restrict__ Bt, float* __restrict__ Cout)
{
    __shared__ u16 As[128 * 64];
    __shared__ u16 Bs[64 * 64];
    int t = threadIdx.x;
    int m0 = blockIdx.y * 128, n0 = blockIdx.x * 64;
    int lane = t & 63, w = t >> 6;
    int mw = (w >> 1) * 64, nw = (w & 1) * 32;
    int mr = lane & 15, quad = lane >> 4;

    f32x4 zero = {0.f, 0.f, 0.f, 0.f};
    f32x4 acc[4][4];
#pragma unroll
    for (int i = 0; i < 4; ++i)
#pragma unroll
        for (int j = 0; j < 4; ++j) acc[i][j] = zero;

    gemm_kloop64<1, 2>(A, Bt, CCH, m0, n0, t, As, Bs, acc);

#pragma unroll
    for (int i = 0; i < 4; ++i)
#pragma unroll
        for (int j = 0; j < 2; ++j) {
            int tok = m0 + mw + i * 16 + mr;
            int cg0 = n0 + nw + j * 16 + quad * 4;
            float4 v;
            v.x = acc[i][j][0]; v.y = acc[i][j][1];
            v.z = acc[i][j][2]; v.w = acc[i][j][3];
            *(float4*)&Cout[(size_t)tok * CCH + cg0] = v;
        }
}

// ---------------- flash attention v11 ----------------
// = v10 (hoisted shared K/V fragments, balanced pairing, cheap softmax)
//   + DOUBLE-BUFFERED K/V LDS with next-chunk prefetch:
//     the 4 global_load_lds for chunk ic+1 are issued right after the
//     top-of-loop barrier, so the compiler's vmcnt(0)-before-barrier drain
//     lands AFTER the chunk's MFMA/softmax work instead of before it.
//   + barriers cut from 2/chunk to 1/chunk (double buffer removes the
//     WAR hazard that forced the trailing barrier).

#define PSTRIDE 72

template<bool MASK>
__device__ __forceinline__ void tile_compute(
    const bf16x8 (&kf)[4][2], const bf16x8 (&vf)[4][2], u16* __restrict__ pb,
    bf16x8 qf0, bf16x8 qf1, int m, int quad, int qcol, int kv0,
    f32x4 (&o)[4], f32x4& ls)
{
    f32x4 zero = {0.f, 0.f, 0.f, 0.f};
    // QK^T -> S^T: kv on quad*4+r (per kc), q on lane&15
    f32x4 st[4];
#pragma unroll
    for (int kc = 0; kc < 4; ++kc) {
        f32x4 s = __builtin_amdgcn_mfma_f32_16x16x32_bf16(kf[kc][0], qf0, zero, 0, 0, 0);
        st[kc]   = __builtin_amdgcn_mfma_f32_16x16x32_bf16(kf[kc][1], qf1, s, 0, 0, 0);
    }
    // exp2, partial row sums, pack -> wave-private P LDS [q][kv]
#pragma unroll
    for (int kc = 0; kc < 4; ++kc) {
        float e0, e1, e2, e3;
#pragma unroll
        for (int r = 0; r < 4; ++r) {
            float v = st[kc][r];
            if (MASK && (kv0 + kc * 16 + quad * 4 + r > qcol)) v = -1e30f;
            float e = __builtin_amdgcn_exp2f(v);
            ls[r] += e;
            if (r == 0) e0 = e; else if (r == 1) e1 = e; else if (r == 2) e2 = e; else e3 = e;
        }
        uint2 pk; pk.x = pk_bf16(e0, e1); pk.y = pk_bf16(e2, e3);
        *(uint2*)&pb[m * PSTRIDE + kc * 16 + quad * 4] = pk;
    }
    // PV: O^T += V^T-frag x P^T-frag
#pragma unroll
    for (int ks = 0; ks < 2; ++ks) {
        bf16x8 pf = *(const bf16x8*)&pb[m * PSTRIDE + ks * 32 + quad * 8];
#pragma unroll
        for (int dg = 0; dg < 4; ++dg)
            o[dg] = __builtin_amdgcn_mfma_f32_16x16x32_bf16(vf[dg][ks], pf, o[dg], 0, 0, 0);
    }
}

__global__ __launch_bounds__(256) void attn_kernel(
    const u16* __restrict__ Q, const u16* __restrict__ K,
    const u16* __restrict__ Vt, u16* __restrict__ Y)
{
    __shared__ u16 Ks[2][64 * 64];
    __shared__ u16 Vs[2][64 * 64];
    __shared__ u16 Pl[4][16 * PSTRIDE];
    int t = threadIdx.x;
    int w = t >> 6, lane = t & 63;
    int m = lane & 15, quad = lane >> 4;

    int bid = blockIdx.x;
    int head = bid & 31;                 // head%8 = bid%8 -> XCD affinity
    int g = bid >> 5;                    // 0..15
    int pr = (g < 8) ? g : 23 - g;       // co-resident pair (bid, bid+256) sums const
    int qbA = pr;                        // light q-block (chunks 0..qbA)
    int qbB = 31 - pr;                   // heavy q-block (chunks 0..qbB)
    int rowA = qbA * 64 + w * 16;
    int rowB = qbB * 64 + w * 16;

    const u16* qpA = Q + ((size_t)head * TT + rowA + m) * HDD + quad * 8;
    const u16* qpB = Q + ((size_t)head * TT + rowB + m) * HDD + quad * 8;
    bf16x8 qA0 = *(const bf16x8*)qpA;
    bf16x8 qA1 = *(const bf16x8*)(qpA + 32);
    bf16x8 qB0 = *(const bf16x8*)qpB;
    bf16x8 qB1 = *(const bf16x8*)(qpB + 32);

    const u16* kbase = K + (size_t)head * TT * HDD;   // [t][d]
    const u16* vbase = Vt + (size_t)head * HDD * TT;  // [d][t]
    u16* pb = &Pl[w][0];

    // staging geometry (lane-contiguous LDS, XOR swizzle on global col-group)
    int lr = lane >> 3;
    int cg = (lane & 7) ^ lr;
    int r0 = w * 16 + lr, r1 = r0 + 8;
    int loff0 = (w * 128 + lane) * 8;        // u16 offset within one buffer
    int loff1 = (w * 128 + 64 + lane) * 8;

    f32x4 zero = {0.f, 0.f, 0.f, 0.f};
    f32x4 oA[4], oB[4], lsA = zero, lsB = zero;
#pragma unroll
    for (int dg = 0; dg < 4; ++dg) { oA[dg] = zero; oB[dg] = zero; }
    int qcolA = rowA + m, qcolB = rowB + m;
    int sw = m & 7;

    // prologue: stage chunk 0 into buffer 0
    async_copy16(kbase + (size_t)r0 * 64 + cg * 8, &Ks[0][loff0]);
    async_copy16(kbase + (size_t)r1 * 64 + cg * 8, &Ks[0][loff1]);
    async_copy16(vbase + (size_t)r0 * TT + cg * 8, &Vs[0][loff0]);
    async_copy16(vbase + (size_t)r1 * TT + cg * 8, &Vs[0][loff1]);

    for (int ic = 0; ic <= qbB; ++ic) {
        int buf = ic & 1;
        int kv0 = ic << 6;
        __syncthreads();            // chunk ic arrived (vmcnt drained); prev compute done
        if (ic < qbB) {             // prefetch chunk ic+1 into the other buffer
            int nkv = kv0 + 64;
            async_copy16(kbase + (size_t)(nkv + r0) * 64 + cg * 8, &Ks[buf ^ 1][loff0]);
            async_copy16(kbase + (size_t)(nkv + r1) * 64 + cg * 8, &Ks[buf ^ 1][loff1]);
            async_copy16(vbase + (size_t)r0 * TT + nkv + cg * 8, &Vs[buf ^ 1][loff0]);
            async_copy16(vbase + (size_t)r1 * TT + nkv + cg * 8, &Vs[buf ^ 1][loff1]);
        }
        // hoisted fragment loads, shared by both paired tiles
        const u16* Kb = Ks[buf];
        const u16* Vb = Vs[buf];
        bf16x8 kf[4][2], vf[4][2];
#pragma unroll
        for (int kc = 0; kc < 4; ++kc) {
            int rr = kc * 16 + m;
            kf[kc][0] = *(const bf16x8*)&Kb[rr * 64 + ((quad ^ sw) << 3)];
            kf[kc][1] = *(const bf16x8*)&Kb[rr * 64 + (((quad + 4) ^ sw) << 3)];
            vf[kc][0] = *(const bf16x8*)&Vb[rr * 64 + ((quad ^ sw) << 3)];
            vf[kc][1] = *(const bf16x8*)&Vb[rr * 64 + (((quad + 4) ^ sw) << 3)];
        }
        if (ic < qbA)
            tile_compute<false>(kf, vf, pb, qA0, qA1, m, quad, qcolA, kv0, oA, lsA);
        else if (ic == qbA)
            tile_compute<true>(kf, vf, pb, qA0, qA1, m, quad, qcolA, kv0, oA, lsA);
        if (ic < qbB)
            tile_compute<false>(kf, vf, pb, qB0, qB1, m, quad, qcolB, kv0, oB, lsB);
        else
            tile_compute<true>(kf, vf, pb, qB0, qB1, m, quad, qcolB, kv0, oB, lsB);
    }

    // row-sum reduce (q on lane&15; partials across quad groups)
    float lA = (lsA[0] + lsA[1]) + (lsA[2] + lsA[3]);
    float lB = (lsB[0] + lsB[1]) + (lsB[2] + lsB[3]);
    lA += __shfl_xor(lA, 16, 64); lA += __shfl_xor(lA, 32, 64);
    lB += __shfl_xor(lB, 16, 64); lB += __shfl_xor(lB, 32, 64);
    float invA = 1.0f / lA, invB = 1.0f / lB;

    int b = head >> 4, h = head & 15;
    size_t roA = ((size_t)(b * TT + rowA + m)) * CCH + h * HDD;
    size_t roB = ((size_t)(b * TT + rowB + m)) * CCH + h * HDD;
#pragma unroll
    for (int dg = 0; dg < 4; ++dg) {
        uint2 ov;
        ov.x = pk_bf16(oA[dg][0] * invA, oA[dg][1] * invA);
        ov.y = pk_bf16(oA[dg][2] * invA, oA[dg][3] * invA);
        *(uint2*)&Y[roA + dg * 16 + quad * 4] = ov;
        ov.x = pk_bf16(oB[dg][0] * invB, oB[dg][1] * invB);
        ov.y = pk_bf16(oB[dg][2] * invB, oB[dg][3] * invB);
        *(uint2*)&Y[roB + dg * 16 + quad * 4] = ov;
    }
}

// ---------------- launch ----------------

extern "C" void kernel_launch(void* const* d_in, const int* in_sizes, int n_in,
                              void* d_out, int out_size, void* d_ws, size_t ws_size,
                              hipStream_t stream) {
    const float* x      = (const float*)d_in[0];
    const float* w_attn = (const float*)d_in[1];
    const float* w_proj = (const float*)d_in[2];
    float* out = (float*)d_out;

    char* ws = (char*)d_ws;
    u16* x_bf   = (u16*)ws; ws += (size_t)M_TOK * CCH * 2;         // 8 MB
    u16* wqkvT  = (u16*)ws; ws += (size_t)N_QKV * CCH * 2;         // 6 MB
    u16* wprojT = (u16*)ws; ws += (size_t)CCH * CCH * 2;           // 2 MB
    u16* qbuf   = (u16*)ws; ws += (size_t)BB * NHH * TT * HDD * 2; // 8 MB
    u16* kbuf   = (u16*)ws; ws += (size_t)BB * NHH * TT * HDD * 2; // 8 MB
    u16* vtb    = (u16*)ws; ws += (size_t)BB * NHH * HDD * TT * 2; // 8 MB
    u16* yb     = (u16*)ws; ws += (size_t)M_TOK * CCH * 2;         // 8 MB

    // softmax scale * log2(e), folded into Q columns of w_attn during transpose
    const float QSC = 0.125f * 1.44269504088896f;

    // 1. cast x -> bf16
    cast_bf16_kernel<<<dim3(M_TOK * CCH / 4 / 256), dim3(256), 0, stream>>>(x, x_bf, M_TOK * CCH / 4);
    // 2. transpose weights -> bf16 [N][K]
    transpose_bf16_kernel<<<dim3(N_QKV / 32, CCH / 32), dim3(32, 8), 0, stream>>>(
        w_attn, wqkvT, CCH, N_QKV, CCH, QSC);
    transpose_bf16_kernel<<<dim3(CCH / 32, CCH / 32), dim3(32, 8), 0, stream>>>(
        w_proj, wprojT, CCH, CCH, 0, 1.0f);
    // 3. merged QKV GEMM: 768 blocks (3/CU), BK=64, swizzled LDS
    qkv_gemm_kernel<<<dim3(24, 32), dim3(256), 0, stream>>>(
        x_bf, wqkvT, qbuf, kbuf, vtb);
    // 4. flash attention v11 (double-buffered prefetch, 1 barrier/chunk)
    attn_kernel<<<dim3(512), dim3(256), 0, stream>>>(qbuf, kbuf, vtb, yb);
    // 5. output projection: 128x64 tiles, BK=64, 512 blocks (2/CU)
    proj_gemm_kernel<<<dim3(16, 32), dim3(256), 0, stream>>>(yb, wprojT, out);
}

// Round 2
// 173.693 us; speedup vs baseline: 1.0036x; 1.0036x over previous
//
#include <hip/hip_runtime.h>
#include <hip/hip_bf16.h>

#define BB 2
#define TT 2048
#define CCH 1024
#define NHH 16
#define HDD 64
#define M_TOK (BB*TT)      // 4096
#define N_QKV (3*CCH)      // 3072

typedef __attribute__((ext_vector_type(8))) short bf16x8;
typedef __attribute__((ext_vector_type(4))) float f32x4;
typedef unsigned short u16;
typedef unsigned int u32;

__device__ __forceinline__ u16 f2bf(float f) {
    union { float f; u32 u; } v; v.f = f;
    u32 u = v.u;
    u32 r = (u + 0x7FFFu + ((u >> 16) & 1u)) >> 16;
    return (u16)r;
}

// pack hi16(a),hi16(b) -> u32 {b.hi<<16 | a.hi} with +0x8000 rounding
__device__ __forceinline__ u32 pk_bf16(float a, float b) {
    u32 ua = __float_as_uint(a) + 0x8000u;
    u32 ub = __float_as_uint(b) + 0x8000u;
    return __builtin_amdgcn_perm(ub, ua, 0x07060302u);
}

__device__ __forceinline__ void async_copy16(const void* g, void* l) {
    __builtin_amdgcn_global_load_lds((__attribute__((address_space(1))) void*)g,
                                     (__attribute__((address_space(3))) void*)l,
                                     16, 0, 0);
}

// ---------------- pre-pass kernels ----------------

__global__ __launch_bounds__(256) void cast_bf16_kernel(
    const float* __restrict__ src, u16* __restrict__ dst, int n4) {
    int i = blockIdx.x * 256 + threadIdx.x;
    if (i < n4) {
        float4 f = ((const float4*)src)[i];
        ushort4 o;
        o.x = f2bf(f.x); o.y = f2bf(f.y); o.z = f2bf(f.z); o.w = f2bf(f.w);
        ((ushort4*)dst)[i] = o;
    }
}

// src [R][Cn] fp32 -> dst [Cn][R] bf16; rows of dst with index < scale_rows get *= sc
__global__ __launch_bounds__(256) void transpose_bf16_kernel(
    const float* __restrict__ src, u16* __restrict__ dst, int R, int Cn,
    int scale_rows, float sc) {
    __shared__ float tile[32][33];
    int c0 = blockIdx.x * 32, r0 = blockIdx.y * 32;
    int tx = threadIdx.x, ty = threadIdx.y;
#pragma unroll
    for (int i = ty; i < 32; i += 8)
        tile[i][tx] = src[(size_t)(r0 + i) * Cn + c0 + tx];
    __syncthreads();
#pragma unroll
    for (int i = ty; i < 32; i += 8) {
        float v = tile[tx][i];
        if (c0 + i < scale_rows) v *= sc;
        dst[(size_t)(c0 + i) * R + r0 + tx] = f2bf(v);
    }
}

// ---------------- shared GEMM K-loop, BK=64, XOR-swizzled LDS ----------------

template<int SWAP, int NJ>
__device__ __forceinline__ void gemm_kloop64(
    const u16* __restrict__ A, const u16* __restrict__ Bt, int K,
    int m0, int n0, int t, u16* __restrict__ As, u16* __restrict__ Bs,
    f32x4 (&acc)[4][4])
{
    int lane = t & 63, w = t >> 6;
    int mw = (w >> 1) * 64, nw = (w & 1) * (NJ * 16);
    int mr = lane & 15, quad = lane >> 4;
    int lr = lane >> 3;                 // row-in-group 0..7
    int cswz = (lane & 7) ^ lr;         // swizzled 16B-chunk on the global side

    const u16* gA[4]; u16* lA[4];
#pragma unroll
    for (int p = 0; p < 4; ++p) {
        int grp = w * 4 + p;            // 16 groups x 8 rows = 128
        gA[p] = A + (size_t)(m0 + grp * 8 + lr) * K + cswz * 8;
        lA[p] = As + ((size_t)grp * 64 + lane) * 8;
    }
    const u16* gB[4]; u16* lB[4];
#pragma unroll
    for (int p = 0; p < NJ; ++p) {
        int grp = w * NJ + p;           // NJ groups per wave
        gB[p] = Bt + (size_t)(n0 + grp * 8 + lr) * K + cswz * 8;
        lB[p] = Bs + ((size_t)grp * 64 + lane) * 8;
    }

    int swm = mr & 7;
    for (int k0 = 0; k0 < K; k0 += 64) {
#pragma unroll
        for (int p = 0; p < 4; ++p) async_copy16(gA[p] + k0, lA[p]);
#pragma unroll
        for (int p = 0; p < NJ; ++p) async_copy16(gB[p] + k0, lB[p]);
        __syncthreads();
#pragma unroll
        for (int kk = 0; kk < 2; ++kk) {
            bf16x8 af[4], bfr[4];
#pragma unroll
            for (int i = 0; i < 4; ++i) {
                int r = mw + i * 16 + mr;
                af[i] = *(const bf16x8*)&As[r * 64 + (((kk * 4 + quad) ^ swm) << 3)];
            }
#pragma unroll
            for (int j = 0; j < NJ; ++j) {
                int r = nw + j * 16 + mr;
                bfr[j] = *(const bf16x8*)&Bs[r * 64 + (((kk * 4 + quad) ^ swm) << 3)];
            }
#pragma unroll
            for (int i = 0; i < 4; ++i)
#pragma unroll
                for (int j = 0; j < NJ; ++j) {
                    if (SWAP)
                        acc[i][j] = __builtin_amdgcn_mfma_f32_16x16x32_bf16(bfr[j], af[i], acc[i][j], 0, 0, 0);
                    else
                        acc[i][j] = __builtin_amdgcn_mfma_f32_16x16x32_bf16(af[i], bfr[j], acc[i][j], 0, 0, 0);
                }
        }
        __syncthreads();
    }
}

// ---------------- merged QKV GEMM: one 768-block dispatch ----------------

__global__ __launch_bounds__(256, 3) void qkv_gemm_kernel(
    const u16* __restrict__ A, const u16* __restrict__ Bt,
    u16* __restrict__ Qo, u16* __restrict__ Ko, u16* __restrict__ Vto)
{
    __shared__ u16 As[128 * 64];
    __shared__ u16 Bs[128 * 64];
    int t = threadIdx.x;
    int m0 = blockIdx.y * 128, n0 = blockIdx.x * 128;
    int part = n0 >> 10;
    int lane = t & 63, w = t >> 6;
    int mw = (w >> 1) * 64, nw = (w & 1) * 64;
    int mr = lane & 15, quad = lane >> 4;

    f32x4 zero = {0.f, 0.f, 0.f, 0.f};
    f32x4 acc[4][4];
#pragma unroll
    for (int i = 0; i < 4; ++i)
#pragma unroll
        for (int j = 0; j < 4; ++j) acc[i][j] = zero;

    if (part < 2) {   // block-uniform branch
        gemm_kloop64<1, 4>(A, Bt, CCH, m0, n0, t, As, Bs, acc);
        u16* dstp = part ? Ko : Qo;
#pragma unroll
        for (int i = 0; i < 4; ++i)
#pragma unroll
            for (int j = 0; j < 4; ++j) {
                int tok = m0 + mw + i * 16 + mr;
                int cg0 = n0 + nw + j * 16 + quad * 4;
                int cc = cg0 & 1023;
                int h = cc >> 6, d0 = cc & 63;
                int b = tok >> 11, tt = tok & 2047;
                int bh = b * NHH + h;
                uint2 o;
                o.x = pk_bf16(acc[i][j][0], acc[i][j][1]);
                o.y = pk_bf16(acc[i][j][2], acc[i][j][3]);
                *(uint2*)&dstp[((size_t)bh * TT + tt) * HDD + d0] = o;
            }
    } else {
        gemm_kloop64<0, 4>(A, Bt, CCH, m0, n0, t, As, Bs, acc);
#pragma unroll
        for (int i = 0; i < 4; ++i)
#pragma unroll
            for (int j = 0; j < 4; ++j) {
                int t0 = m0 + mw + i * 16 + quad * 4;
                int cg = n0 + nw + j * 16 + mr;
                int cc = cg & 1023;
                int h = cc >> 6, d = cc & 63;
                int b = t0 >> 11, tt0 = t0 & 2047;
                int bh = b * NHH + h;
                uint2 o;
                o.x = pk_bf16(acc[i][j][0], acc[i][j][1]);
                o.y = pk_bf16(acc[i][j][2], acc[i][j][3]);
                *(uint2*)&Vto[((size_t)bh * HDD + d) * TT + tt0] = o;
            }
    }
}

// ---------------- output projection: 128x64 tiles, 512 blocks (2/CU) ----------------

__global__ __launch_bounds__(256) void proj_gemm_kernel(
    const u16* __restrict__ A, const u16* __restrict__ Bt, float* __restrict__ Cout)
{
    __shared__ u16 As[128 * 64];
    __shared__ u16 Bs[64 * 64];
    int t = threadIdx.x;
    int m0 = blockIdx.y * 128, n0 = blockIdx.x * 64;
    int lane = t & 63, w = t >> 6;
    int mw = (w >> 1) * 64, nw = (w & 1) * 32;
    int mr = lane & 15, quad = lane >> 4;

    f32x4 zero = {0.f, 0.f, 0.f, 0.f};
    f32x4 acc[4][4];
#pragma unroll
    for (int i = 0; i < 4; ++i)
#pragma unroll
        for (int j = 0; j < 4; ++j) acc[i][j] = zero;

    gemm_kloop64<1, 2>(A, Bt, CCH, m0, n0, t, As, Bs, acc);

#pragma unroll
    for (int i = 0; i < 4; ++i)
#pragma unroll
        for (int j = 0; j < 2; ++j) {
            int tok = m0 + mw + i * 16 + mr;
            int cg0 = n0 + nw + j * 16 + quad * 4;
            float4 v;
            v.x = acc[i][j][0]; v.y = acc[i][j][1];
            v.z = acc[i][j][2]; v.w = acc[i][j][3];
            *(float4*)&Cout[(size_t)tok * CCH + cg0] = v;
        }
}

// ---------------- flash attention v12: kv-split waves ----------------
// v11 was LDS-BW bound (~27 of 43.8 us): 4 waves each read the FULL 16 KB
// K/V fragment set per chunk (identical data, per-wave MFMA duplicates it).
// v12 remaps the 4 waves: (iq = q-slice of 32 rows) x (kh = kv-half of 32).
// Each wave reads only its 32-kv half of K (4 b128) and the matching V
// k-slice (4 b128) = 8 KB/chunk (was 16). MFMA count, P volume, staging and
// the light/heavy A/B pairing (causal balance) are unchanged. O and row-sums
// are partial over kv -> one cross-kh combine through LDS after the loop.

#define PST2 40   // P row stride (u16): 16B-aligned rows, 2-way-max banks

template<bool MASK>
__device__ __forceinline__ void tile2(
    const bf16x8 (&kf)[2][2], const bf16x8 (&vf)[4], u16* __restrict__ pb,
    const bf16x8 (&qf)[2][2], int m, int quad, int kvb, int qcol0,
    f32x4 (&o)[2][4], f32x4 (&ls)[2])
{
    f32x4 zero = {0.f, 0.f, 0.f, 0.f};
#pragma unroll
    for (int ms = 0; ms < 2; ++ms) {
#pragma unroll
        for (int kc = 0; kc < 2; ++kc) {
            // S^T: kv = kvb + kc*16 + quad*4 + r (rows), q = qcol0 + ms*16 (cols)
            f32x4 s  = __builtin_amdgcn_mfma_f32_16x16x32_bf16(kf[kc][0], qf[ms][0], zero, 0, 0, 0);
            f32x4 st = __builtin_amdgcn_mfma_f32_16x16x32_bf16(kf[kc][1], qf[ms][1], s, 0, 0, 0);
            float e0, e1, e2, e3;
#pragma unroll
            for (int r = 0; r < 4; ++r) {
                float v = st[r];
                if (MASK && (kvb + kc * 16 + quad * 4 + r > qcol0 + ms * 16)) v = -1e30f;
                float e = __builtin_amdgcn_exp2f(v);
                ls[ms][r] += e;
                if (r == 0) e0 = e; else if (r == 1) e1 = e; else if (r == 2) e2 = e; else e3 = e;
            }
            uint2 pk; pk.x = pk_bf16(e0, e1); pk.y = pk_bf16(e2, e3);
            *(uint2*)&pb[(ms * 16 + m) * PST2 + kc * 16 + quad * 4] = pk;
        }
    }
    // PV over this wave's 32-kv slice: one K=32 MFMA step
#pragma unroll
    for (int ms = 0; ms < 2; ++ms) {
        bf16x8 pf = *(const bf16x8*)&pb[(ms * 16 + m) * PST2 + quad * 8];
#pragma unroll
        for (int dg = 0; dg < 4; ++dg)
            o[ms][dg] = __builtin_amdgcn_mfma_f32_16x16x32_bf16(vf[dg], pf, o[ms][dg], 0, 0, 0);
    }
}

// smem carve (u16 units): Ks dbuf [0,8192), Vs dbuf [8192,16384),
// P 4 waves x 1280 [16384,21504), l-exchange 128 f32 [21504,21760)
#define SM_U16 21760

__global__ __launch_bounds__(256, 2) void attn_kernel(
    const u16* __restrict__ Q, const u16* __restrict__ K,
    const u16* __restrict__ Vt, u16* __restrict__ Y)
{
    __shared__ u16 smem[SM_U16];
    int t = threadIdx.x;
    int w = t >> 6, lane = t & 63;
    int m = lane & 15, quad = lane >> 4;
    int iq = w >> 1, kh = w & 1;

    int bid = blockIdx.x;
    int head = bid & 31;                 // head%8 = bid%8 -> XCD affinity
    int g = bid >> 5;                    // 0..15
    int pr = (g < 8) ? g : 23 - g;       // co-resident pair (bid, bid+256) sums const
    int qbA = pr;                        // light q-block (chunks 0..qbA)
    int qbB = 31 - pr;                   // heavy q-block (chunks 0..qbB)
    int rbA = qbA * 64 + iq * 32;
    int rbB = qbB * 64 + iq * 32;

    const u16* qpA = Q + ((size_t)head * TT + rbA + m) * HDD + quad * 8;
    const u16* qpB = Q + ((size_t)head * TT + rbB + m) * HDD + quad * 8;
    bf16x8 qfA[2][2], qfB[2][2];
    qfA[0][0] = *(const bf16x8*)qpA;
    qfA[0][1] = *(const bf16x8*)(qpA + 32);
    qfA[1][0] = *(const bf16x8*)(qpA + 16 * HDD);
    qfA[1][1] = *(const bf16x8*)(qpA + 16 * HDD + 32);
    qfB[0][0] = *(const bf16x8*)qpB;
    qfB[0][1] = *(const bf16x8*)(qpB + 32);
    qfB[1][0] = *(const bf16x8*)(qpB + 16 * HDD);
    qfB[1][1] = *(const bf16x8*)(qpB + 16 * HDD + 32);

    const u16* kbase = K + (size_t)head * TT * HDD;   // [t][d]
    const u16* vbase = Vt + (size_t)head * HDD * TT;  // [d][t]
    u16* pb = smem + 16384 + w * (32 * PST2);

    // staging geometry (lane-contiguous LDS, XOR swizzle on global col-group)
    int lr = lane >> 3;
    int cg = (lane & 7) ^ lr;
    int r0 = w * 16 + lr, r1 = r0 + 8;
    int loff0 = (w * 128 + lane) * 8;    // u16 offset within one 4096-u16 buffer
    int loff1 = loff0 + 512;

    f32x4 zero = {0.f, 0.f, 0.f, 0.f};
    f32x4 oA[2][4], oB[2][4], lsA[2], lsB[2];
#pragma unroll
    for (int ms = 0; ms < 2; ++ms) {
        lsA[ms] = zero; lsB[ms] = zero;
#pragma unroll
        for (int dg = 0; dg < 4; ++dg) { oA[ms][dg] = zero; oB[ms][dg] = zero; }
    }
    int qcA = rbA + m, qcB = rbB + m;
    int sw = m & 7;

    // prologue: stage chunk 0 into buffer 0
    async_copy16(kbase + (size_t)r0 * 64 + cg * 8, smem + loff0);
    async_copy16(kbase + (size_t)r1 * 64 + cg * 8, smem + loff1);
    async_copy16(vbase + (size_t)r0 * TT + cg * 8, smem + 8192 + loff0);
    async_copy16(vbase + (size_t)r1 * TT + cg * 8, smem + 8192 + loff1);

    for (int ic = 0; ic <= qbB; ++ic) {
        int buf = ic & 1;
        int kv0 = ic << 6;
        __syncthreads();            // chunk ic arrived; prev compute done
        if (ic < qbB) {             // prefetch chunk ic+1 into the other buffer
            int nkv = kv0 + 64;
            u16* dK = smem + (buf ^ 1) * 4096;
            u16* dV = smem + 8192 + (buf ^ 1) * 4096;
            async_copy16(kbase + (size_t)(nkv + r0) * 64 + cg * 8, dK + loff0);
            async_copy16(kbase + (size_t)(nkv + r1) * 64 + cg * 8, dK + loff1);
            async_copy16(vbase + (size_t)r0 * TT + nkv + cg * 8, dV + loff0);
            async_copy16(vbase + (size_t)r1 * TT + nkv + cg * 8, dV + loff1);
        }
        const u16* Kb = smem + buf * 4096;
        const u16* Vb = smem + 8192 + buf * 4096;
        // per-wave fragments: only this wave's 32-kv half (8 b128 total)
        bf16x8 kf[2][2], vf[4];
#pragma unroll
        for (int kc = 0; kc < 2; ++kc) {
            int rr = kh * 32 + kc * 16 + m;
            kf[kc][0] = *(const bf16x8*)&Kb[rr * 64 + ((quad ^ sw) << 3)];
            kf[kc][1] = *(const bf16x8*)&Kb[rr * 64 + (((quad + 4) ^ sw) << 3)];
        }
#pragma unroll
        for (int dg = 0; dg < 4; ++dg) {
            int rr = dg * 16 + m;
            vf[dg] = *(const bf16x8*)&Vb[rr * 64 + (((kh * 4 + quad) ^ sw) << 3)];
        }
        int kvb = kv0 + kh * 32;
        if (ic < qbA)
            tile2<false>(kf, vf, pb, qfA, m, quad, kvb, qcA, oA, lsA);
        else if (ic == qbA)
            tile2<true >(kf, vf, pb, qfA, m, quad, kvb, qcA, oA, lsA);
        if (ic < qbB)
            tile2<false>(kf, vf, pb, qfB, m, quad, kvb, qcB, oB, lsB);
        else
            tile2<true >(kf, vf, pb, qfB, m, quad, kvb, qcB, oB, lsB);
    }

    // per-wave row-sums (partial over this wave's kv half)
    float lv[2][2];
#pragma unroll
    for (int p = 0; p < 2; ++p)
#pragma unroll
        for (int ms = 0; ms < 2; ++ms) {
            f32x4 L = p ? lsB[ms] : lsA[ms];
            float l = (L[0] + L[1]) + (L[2] + L[3]);
            l += __shfl_xor(l, 16, 64);
            l += __shfl_xor(l, 32, 64);
            lv[p][ms] = l;
        }

    // cross-kh combine: kh=1 writes its O-partials + l, kh=0 merges & stores
    __syncthreads();
    f32x4* ob = (f32x4*)smem;                 // overlays Ks/Vs (done with them)
    float* lb = (float*)&smem[21504];         // 128 floats
    if (kh) {
        f32x4* dst = ob + (size_t)iq * 1024 + lane;
#pragma unroll
        for (int ms = 0; ms < 2; ++ms)
#pragma unroll
            for (int dg = 0; dg < 4; ++dg) {
                dst[((0 + ms) * 4 + dg) * 64] = oA[ms][dg];
                dst[((2 + ms) * 4 + dg) * 64] = oB[ms][dg];
            }
        if (quad == 0) {
#pragma unroll
            for (int ms = 0; ms < 2; ++ms) {
                lb[(iq * 4 + 0 + ms) * 16 + m] = lv[0][ms];
                lb[(iq * 4 + 2 + ms) * 16 + m] = lv[1][ms];
            }
        }
    }
    __syncthreads();
    if (!kh) {
        f32x4* src = ob + (size_t)iq * 1024 + lane;
        float lA[2], lB[2];
#pragma unroll
        for (int ms = 0; ms < 2; ++ms) {
#pragma unroll
            for (int dg = 0; dg < 4; ++dg) {
                oA[ms][dg] += src[((0 + ms) * 4 + dg) * 64];
                oB[ms][dg] += src[((2 + ms) * 4 + dg) * 64];
            }
            lA[ms] = lv[0][ms] + lb[(iq * 4 + 0 + ms) * 16 + m];
            lB[ms] = lv[1][ms] + lb[(iq * 4 + 2 + ms) * 16 + m];
        }
        int b = head >> 4, h = head & 15;
#pragma unroll
        for (int ms = 0; ms < 2; ++ms) {
            float invA = 1.0f / lA[ms], invB = 1.0f / lB[ms];
            size_t roA = ((size_t)(b * TT + rbA + ms * 16 + m)) * CCH + h * HDD;
            size_t roB = ((size_t)(b * TT + rbB + ms * 16 + m)) * CCH + h * HDD;
#pragma unroll
            for (int dg = 0; dg < 4; ++dg) {
                uint2 ov;
                ov.x = pk_bf16(oA[ms][dg][0] * invA, oA[ms][dg][1] * invA);
                ov.y = pk_bf16(oA[ms][dg][2] * invA, oA[ms][dg][3] * invA);
                *(uint2*)&Y[roA + dg * 16 + quad * 4] = ov;
                ov.x = pk_bf16(oB[ms][dg][0] * invB, oB[ms][dg][1] * invB);
                ov.y = pk_bf16(oB[ms][dg][2] * invB, oB[ms][dg][3] * invB);
                *(uint2*)&Y[roB + dg * 16 + quad * 4] = ov;
            }
        }
    }
}

// ---------------- launch ----------------

extern "C" void kernel_launch(void* const* d_in, const int* in_sizes, int n_in,
                              void* d_out, int out_size, void* d_ws, size_t ws_size,
                              hipStream_t stream) {
    const float* x      = (const float*)d_in[0];
    const float* w_attn = (const float*)d_in[1];
    const float* w_proj = (const float*)d_in[2];
    float* out = (float*)d_out;

    char* ws = (char*)d_ws;
    u16* x_bf   = (u16*)ws; ws += (size_t)M_TOK * CCH * 2;         // 8 MB
    u16* wqkvT  = (u16*)ws; ws += (size_t)N_QKV * CCH * 2;         // 6 MB
    u16* wprojT = (u16*)ws; ws += (size_t)CCH * CCH * 2;           // 2 MB
    u16* qbuf   = (u16*)ws; ws += (size_t)BB * NHH * TT * HDD * 2; // 8 MB
    u16* kbuf   = (u16*)ws; ws += (size_t)BB * NHH * TT * HDD * 2; // 8 MB
    u16* vtb    = (u16*)ws; ws += (size_t)BB * NHH * HDD * TT * 2; // 8 MB
    u16* yb     = (u16*)ws; ws += (size_t)M_TOK * CCH * 2;         // 8 MB

    // softmax scale * log2(e), folded into Q columns of w_attn during transpose
    const float QSC = 0.125f * 1.44269504088896f;

    // 1. cast x -> bf16
    cast_bf16_kernel<<<dim3(M_TOK * CCH / 4 / 256), dim3(256), 0, stream>>>(x, x_bf, M_TOK * CCH / 4);
    // 2. transpose weights -> bf16 [N][K]
    transpose_bf16_kernel<<<dim3(N_QKV / 32, CCH / 32), dim3(32, 8), 0, stream>>>(
        w_attn, wqkvT, CCH, N_QKV, CCH, QSC);
    transpose_bf16_kernel<<<dim3(CCH / 32, CCH / 32), dim3(32, 8), 0, stream>>>(
        w_proj, wprojT, CCH, CCH, 0, 1.0f);
    // 3. merged QKV GEMM: 768 blocks (3/CU), BK=64, swizzled LDS
    qkv_gemm_kernel<<<dim3(24, 32), dim3(256), 0, stream>>>(
        x_bf, wqkvT, qbuf, kbuf, vtb);
    // 4. flash attention v12 (kv-split waves: half the K/V fragment LDS traffic)
    attn_kernel<<<dim3(512), dim3(256), 0, stream>>>(qbuf, kbuf, vtb, yb);
    // 5. output projection: 128x64 tiles, BK=64, 512 blocks (2/CU)
    proj_gemm_kernel<<<dim3(16, 32), dim3(256), 0, stream>>>(yb, wprojT, out);
}